// Round 1
// baseline (328.678 us; speedup 1.0000x reference)
//
#include <hip/hip_runtime.h>

// Problem constants
static constexpr int NN = 10000;   // nodes
static constexpr int DD = 64;      // in/out dim
static constexpr int KP = 10240;   // padded K for M_T (multiple of BK)
static constexpr int BK = 128;     // K tile
static constexpr int NIT = 79;     // ceil(10000/128)
static constexpr int BM = 64;      // rows per block
static constexpr int LDSROW = 136; // 128 + 8 halfword pad (272 B stride -> 2-way banks, free)

typedef __attribute__((ext_vector_type(4))) float f32x4;
typedef __attribute__((ext_vector_type(8))) short s16x8;

__device__ __forceinline__ unsigned short f2bf(float f) {
  // fp32 -> bf16 round-to-nearest-even (bit trick; inputs finite)
  unsigned u = __float_as_uint(f);
  return (unsigned short)((u + 0x7fffu + ((u >> 16) & 1u)) >> 16);
}

// ---------- prep: M_T[r][d][k] = bf16( sum_j H[k][j] * W_r[d][j] ), zero-padded to KP ----------
__global__ void prep_kernel(const float* __restrict__ H,
                            const float* __restrict__ W1,
                            const float* __restrict__ W2,
                            const float* __restrict__ W3,
                            unsigned short* __restrict__ mt) {
  const int r = blockIdx.y;
  const float* W = (r == 0) ? W1 : (r == 1) ? W2 : W3;
  const int wave = threadIdx.x >> 6;
  const int lane = threadIdx.x & 63;   // lane == output dim d
  f32x4 wr[16];
#pragma unroll
  for (int i = 0; i < 16; ++i) wr[i] = *(const f32x4*)&W[lane * 64 + i * 4];
  unsigned short* orow = mt + ((size_t)r * 64 + lane) * KP;
  const int kbase = blockIdx.x * 128 + wave * 32;
  for (int i = 0; i < 32; ++i) {
    const int k = kbase + i;
    if (k < NN) {
      float s = 0.f;
#pragma unroll
      for (int j = 0; j < 16; ++j) {
        f32x4 h = *(const f32x4*)&H[(size_t)k * 64 + j * 4]; // wave-uniform addr -> broadcast
        s += h[0] * wr[j][0] + h[1] * wr[j][1] + h[2] * wr[j][2] + h[3] * wr[j][3];
      }
      orow[k] = f2bf(s);
    } else {
      orow[k] = 0;  // zero pad k in [10000,10240)
    }
  }
}

// ---------- init: out[v][d] = bias[d] ----------
__global__ void init_out_kernel(const float* __restrict__ bias, float* __restrict__ out) {
  const int i = blockIdx.x * 256 + threadIdx.x;
  if (i < NN * DD) out[i] = bias[i & 63];
}

// ---------- main: out += A_r @ M_r  (bf16 MFMA, A streamed fp32->bf16) ----------
__global__ __launch_bounds__(256) void gcn_main(const float* __restrict__ A1,
                                                const float* __restrict__ A2,
                                                const float* __restrict__ A3,
                                                const unsigned short* __restrict__ mt,
                                                float* __restrict__ out) {
  __shared__ __align__(16) unsigned short mlds[2 * 64 * LDSROW];

  const int r = blockIdx.y;
  const float* A = (r == 0) ? A1 : (r == 1) ? A2 : A3;
  const unsigned short* mtr = mt + (size_t)r * 64 * KP;

  const int wave = threadIdx.x >> 6;
  const int lane = threadIdx.x & 63;
  const int l15 = lane & 15;
  const int lhi = lane >> 4;
  const int v0 = blockIdx.x * BM;

  // A row this lane streams (clamped for tail block; garbage rows never stored)
  int vA = v0 + wave * 16 + l15;
  if (vA > NN - 1) vA = NN - 1;
  const float* arow = A + (size_t)vA * NN;

  // M staging assignment: wave stages rows [16w,16w+16); lane -> (row, 64B segment)
  const int srow = wave * 16 + l15;
  const int sseg = lhi;
  const unsigned short* mrow = mtr + (size_t)srow * KP + sseg * 32;

  f32x4 acc[4] = {{0.f,0.f,0.f,0.f},{0.f,0.f,0.f,0.f},{0.f,0.f,0.f,0.f},{0.f,0.f,0.f,0.f}};
  f32x4 aF[4][2], aN[4][2];
  s16x8 mS[4];

  auto loadM = [&](int t) {
#pragma unroll
    for (int j = 0; j < 4; ++j) mS[j] = *(const s16x8*)(mrow + (size_t)t * BK + j * 8);
  };
  auto writeM = [&](int buf) {
    unsigned short* base = &mlds[buf * 64 * LDSROW + srow * LDSROW];
#pragma unroll
    for (int j = 0; j < 4; ++j) *(s16x8*)(base + (sseg * 4 + j) * 8) = mS[j];
  };
  auto loadA = [&](f32x4 (&a)[4][2], int t, bool guard) {
    const int kb = t * BK;
#pragma unroll
    for (int kk = 0; kk < 4; ++kk) {
      const int kf = kb + kk * 32 + lhi * 8;
      if (!guard) {
        a[kk][0] = *(const f32x4*)(arow + kf);
        a[kk][1] = *(const f32x4*)(arow + kf + 4);
      } else {
        f32x4 z = {0.f, 0.f, 0.f, 0.f};
        a[kk][0] = (kf < NN) ? *(const f32x4*)(arow + kf) : z;
        a[kk][1] = (kf + 4 < NN) ? *(const f32x4*)(arow + kf + 4) : z;
      }
    }
  };
  auto cvtA = [&](const f32x4& x, const f32x4& y) -> s16x8 {
    s16x8 v;
    v[0] = (short)f2bf(x[0]); v[1] = (short)f2bf(x[1]);
    v[2] = (short)f2bf(x[2]); v[3] = (short)f2bf(x[3]);
    v[4] = (short)f2bf(y[0]); v[5] = (short)f2bf(y[1]);
    v[6] = (short)f2bf(y[2]); v[7] = (short)f2bf(y[3]);
    return v;
  };

  // prologue: stage iter 0
  loadM(0);
  loadA(aF, 0, false);
  writeM(0);
  __syncthreads();

  for (int t = 0; t < NIT; ++t) {
    const int buf = t & 1;
    const bool pref = (t + 1 < NIT);
    if (pref) {
      loadM(t + 1);                       // global -> regs (L2-resident M)
      loadA(aN, t + 1, (t + 1 == NIT - 1)); // prefetch next A frags
    }
#pragma unroll
    for (int kk = 0; kk < 4; ++kk) {
      s16x8 a = cvtA(aF[kk][0], aF[kk][1]);
#pragma unroll
      for (int dt = 0; dt < 4; ++dt) {
        // B frag: M[k][d] for d = dt*16+l15, k granule = kk*4+lhi (16B ds_read_b128)
        s16x8 b = *(const s16x8*)&mlds[buf * 64 * LDSROW + (dt * 16 + l15) * LDSROW + (kk * 4 + lhi) * 8];
        acc[dt] = __builtin_amdgcn_mfma_f32_16x16x32_bf16(a, b, acc[dt], 0, 0, 0);
      }
    }
    if (pref) writeM(buf ^ 1);
    __syncthreads();
    if (pref) {
#pragma unroll
      for (int kk = 0; kk < 4; ++kk) { aF[kk][0] = aN[kk][0]; aF[kk][1] = aN[kk][1]; }
    }
  }

  // epilogue: C layout col=lane&15, row=(lane>>4)*4+i (m89-verified)
#pragma unroll
  for (int dt = 0; dt < 4; ++dt) {
    const int d = dt * 16 + l15;
#pragma unroll
    for (int i = 0; i < 4; ++i) {
      const int v = v0 + wave * 16 + lhi * 4 + i;
      if (v < NN) atomicAdd(&out[(size_t)v * DD + d], acc[dt][i]);
    }
  }
}

extern "C" void kernel_launch(void* const* d_in, const int* in_sizes, int n_in,
                              void* d_out, int out_size, void* d_ws, size_t ws_size,
                              hipStream_t stream) {
  const float* H    = (const float*)d_in[0];
  const float* A1   = (const float*)d_in[1];
  const float* A2   = (const float*)d_in[2];
  const float* A3   = (const float*)d_in[3];
  const float* W1   = (const float*)d_in[4];
  const float* W2   = (const float*)d_in[5];
  const float* W3   = (const float*)d_in[6];
  const float* bias = (const float*)d_in[7];
  float* out = (float*)d_out;
  unsigned short* mt = (unsigned short*)d_ws;  // M_T[3][64][KP] bf16 = 3.75 MB

  prep_kernel<<<dim3(KP / 128, 3), 256, 0, stream>>>(H, W1, W2, W3, mt);
  init_out_kernel<<<dim3((NN * DD + 255) / 256), 256, 0, stream>>>(bias, out);
  gcn_main<<<dim3((NN + BM - 1) / BM, 3), 256, 0, stream>>>(A1, A2, A3, mt, out);
}